// Round 14
// baseline (490.693 us; speedup 1.0000x reference)
//
#include <hip/hip_runtime.h>

// profileperm VQ encode+decode, bit-exact vs fp32-numpy reference.
// Round-13 counters: 366us, VALUBusy 73%, WRITE fixed at 131MB, FETCH 70MB -> VALU-bound.
// This round: pack the 2 rows/lane into v_pk_fma_f32 (VOP3P packed fp32, IEEE per
// component -> bit-exact identical scores). 18 scalar FMA -> 9 packed ops per centroid.
// Also removed the gather->writeback barrier (column sets are wave-disjoint; each wave
// reads its 8 columns into registers before overwriting them in place).

typedef float v2f __attribute__((ext_vector_type(2)));

constexpr int N_ROWS = 262144;
constexpr int D   = 128;
constexpr int NB  = 16;   // blocks (== waves per workgroup)
constexpr int NC  = 256;  // centroids per block
constexpr int BD  = 8;    // block dim
constexpr int TPB = 1024; // 16 waves
constexpr int R   = 128;  // rows per chunk
constexpr int PS  = 132;  // padded LDS row stride (floats); 528 B, 16B-aligned
constexpr int GRID_X = 512;              // 2 workgroups per CU
constexpr int CHUNKS = N_ROWS / R;       // 2048 (4 chunks/WG)

static __device__ __forceinline__ v2f splat2(float v) { v2f r; r.x = v; r.y = v; return r; }

__global__ __launch_bounds__(TPB, 8)
void vq_pk(const float* __restrict__ x,
           const float* __restrict__ cent,
           const int*   __restrict__ perm,
           float*       __restrict__ out) {
  extern __shared__ float xs[];   // [R][PS]
  const int t    = threadIdx.x;
  const int wave = t >> 6;
  const int lane = t & 63;

  int pc[BD];  // permuted columns for this wave's block (wave-uniform values)
#pragma unroll
  for (int j = 0; j < BD; ++j) pc[j] = perm[wave * BD + j];

  // Compiler-visible uniform codebook base -> scalar loads in the hot loop.
  const int rb = __builtin_amdgcn_readfirstlane(wave);
  const float* cbase = cent + (size_t)rb * (NC * BD);

  // Per-wave distributed c2 (numpy pairwise tree, bit-exact): lane holds c = k*64+lane.
  float c2v[4];
#pragma unroll
  for (int k = 0; k < 4; ++k) {
    const float* c = cbase + (size_t)(k * 64 + lane) * BD;
    const float q0 = __fmul_rn(c[0], c[0]);
    const float q1 = __fmul_rn(c[1], c[1]);
    const float q2 = __fmul_rn(c[2], c[2]);
    const float q3 = __fmul_rn(c[3], c[3]);
    const float q4 = __fmul_rn(c[4], c[4]);
    const float q5 = __fmul_rn(c[5], c[5]);
    const float q6 = __fmul_rn(c[6], c[6]);
    const float q7 = __fmul_rn(c[7], c[7]);
    c2v[k] = __fadd_rn(__fadd_rn(__fadd_rn(q0, q1), __fadd_rn(q2, q3)),
                       __fadd_rn(__fadd_rn(q4, q5), __fadd_rn(q6, q7)));
  }

  for (int chunk = blockIdx.x; chunk < CHUNKS; chunk += GRID_X) {
    const size_t base = (size_t)chunk * R * D;

    // ---- stage in: 128 rows x 128 cols, fully coalesced float4 ----
#pragma unroll
    for (int k = 0; k < 4; ++k) {
      const int f   = t + k * TPB;        // float4 index 0..4095
      const int row = f >> 5;
      const int col = (f & 31) << 2;
      const float4 v = *reinterpret_cast<const float4*>(x + base + (size_t)f * 4);
      *reinterpret_cast<float4*>(&xs[row * PS + col]) = v;
    }
    __syncthreads();

    // ---- gather this wave's 8 permuted cols, 2 rows/lane packed into v2f ----
    // (no barrier needed after this: each wave reads/writes ONLY its own 8 columns,
    //  and reads them into registers before the in-place winner write below)
    v2f x2[BD];
#pragma unroll
    for (int j = 0; j < BD; ++j) {
      x2[j].x = xs[lane * PS + pc[j]];
      x2[j].y = xs[(lane + 64) * PS + pc[j]];
    }

    v2f m1 = splat2(__builtin_inff());
    int i1lo = 0, i1hi = 0;

#pragma unroll
    for (int k = 0; k < 4; ++k) {
#pragma unroll 4
      for (int cc = 0; cc < 64; ++cc) {
        const int c = k * 64 + cc;
        const float* cp = cbase + c * BD;   // uniform address -> scalar loads
        const float c0 = cp[0], c1 = cp[1], c2_ = cp[2], c3 = cp[3];
        const float c4 = cp[4], c5 = cp[5], c6 = cp[6], c7 = cp[7];
        const float csq = __uint_as_float(
            __builtin_amdgcn_readlane(__float_as_uint(c2v[k]), cc));

        // Packed sgemm chain: per component identical to
        //   fl(x0*c0); fmaf(xk,ck,acc)...; fmaf(-2,acc,c2)   (bit-exact)
        v2f d = x2[0] * splat2(c0);                       // v_pk_mul_f32
        d = __builtin_elementwise_fma(x2[1], splat2(c1), d);
        d = __builtin_elementwise_fma(x2[2], splat2(c2_), d);
        d = __builtin_elementwise_fma(x2[3], splat2(c3), d);
        d = __builtin_elementwise_fma(x2[4], splat2(c4), d);
        d = __builtin_elementwise_fma(x2[5], splat2(c5), d);
        d = __builtin_elementwise_fma(x2[6], splat2(c6), d);
        d = __builtin_elementwise_fma(x2[7], splat2(c7), d);
        const v2f s = __builtin_elementwise_fma(splat2(-2.0f), d, splat2(csq));

        const bool lo = s.x < m1.x;      // strict <: first-min == np.argmin
        const bool hi = s.y < m1.y;
        m1.x = lo ? s.x : m1.x;
        m1.y = hi ? s.y : m1.y;
        i1lo = lo ? c : i1lo;
        i1hi = hi ? c : i1hi;
      }
    }

    // ---- winners -> LDS tile (in place), bit-exact centroid pass-through ----
    {
      const float4 wa0 = *reinterpret_cast<const float4*>(cbase + (size_t)i1lo * BD);
      const float4 wb0 = *reinterpret_cast<const float4*>(cbase + (size_t)i1lo * BD + 4);
      float* o0 = &xs[lane * PS];
      o0[pc[0]] = wa0.x; o0[pc[1]] = wa0.y; o0[pc[2]] = wa0.z; o0[pc[3]] = wa0.w;
      o0[pc[4]] = wb0.x; o0[pc[5]] = wb0.y; o0[pc[6]] = wb0.z; o0[pc[7]] = wb0.w;
      const float4 wa1 = *reinterpret_cast<const float4*>(cbase + (size_t)i1hi * BD);
      const float4 wb1 = *reinterpret_cast<const float4*>(cbase + (size_t)i1hi * BD + 4);
      float* o1 = &xs[(lane + 64) * PS];
      o1[pc[0]] = wa1.x; o1[pc[1]] = wa1.y; o1[pc[2]] = wa1.z; o1[pc[3]] = wa1.w;
      o1[pc[4]] = wb1.x; o1[pc[5]] = wb1.y; o1[pc[6]] = wb1.z; o1[pc[7]] = wb1.w;
    }
    __syncthreads();   // all winner-writes visible before stage-out

    // ---- stage out: fully coalesced float4 ----
#pragma unroll
    for (int k = 0; k < 4; ++k) {
      const int f   = t + k * TPB;
      const int row = f >> 5;
      const int col = (f & 31) << 2;
      const float4 v = *reinterpret_cast<const float4*>(&xs[row * PS + col]);
      *reinterpret_cast<float4*>(out + base + (size_t)f * 4) = v;
    }
    __syncthreads();   // protect next chunk's stage-in
  }
}

extern "C" void kernel_launch(void* const* d_in, const int* in_sizes, int n_in,
                              void* d_out, int out_size, void* d_ws, size_t ws_size,
                              hipStream_t stream) {
  const float* x    = (const float*)d_in[0];
  const float* cent = (const float*)d_in[1];
  const int*   perm = (const int*)d_in[2];
  float*       out  = (float*)d_out;

  const size_t lds_bytes = (size_t)R * PS * sizeof(float); // 67584
  (void)hipFuncSetAttribute(reinterpret_cast<const void*>(&vq_pk),
                            hipFuncAttributeMaxDynamicSharedMemorySize,
                            (int)lds_bytes);

  vq_pk<<<dim3(GRID_X), dim3(TPB), lds_bytes, stream>>>(x, cent, perm, out);
}